// Round 9
// baseline (22552.846 us; speedup 1.0000x reference)
//
#include <hip/hip_runtime.h>
#include <hip/hip_bf16.h>
#include <cstdint>
#include <cstddef>

#define BB 32
#define TT 512

typedef short s8v __attribute__((ext_vector_type(8)));
typedef float f4v __attribute__((ext_vector_type(4)));
typedef unsigned long long u64;
typedef unsigned short u16;
typedef unsigned int u32;

__device__ __forceinline__ short f2b(float x) {
  __hip_bfloat16 h = __float2bfloat16(x);
  return *reinterpret_cast<short*>(&h);
}
__device__ __forceinline__ float b2f(u16 x) {
  __hip_bfloat16 h = *reinterpret_cast<__hip_bfloat16*>(&x);
  return __bfloat162float(h);
}
__device__ __forceinline__ float sigm(float x) { return 1.f / (1.f + __expf(-x)); }

// LLC-coherent pipelined 16B load; caller must vm_wait0() before use.
__device__ __forceinline__ f4v load16_sc(const void* p) {
  f4v v;
  asm volatile("global_load_dwordx4 %0, %1, off sc0 sc1" : "=v"(v) : "v"(p));
  return v;
}
__device__ __forceinline__ void vm_wait0() {
  asm volatile("s_waitcnt vmcnt(0)" ::: "memory");
}
// Lean barriers: raw s_barrier with ONLY the counter correctness needs.
__device__ __forceinline__ void bar0() {
  asm volatile("" ::: "memory");
  __builtin_amdgcn_s_barrier();
  asm volatile("" ::: "memory");
}
__device__ __forceinline__ void bar_lgkm() {
  asm volatile("s_waitcnt lgkmcnt(0)" ::: "memory");
  __builtin_amdgcn_s_barrier();
  asm volatile("" ::: "memory");
}
__device__ __forceinline__ u32 ldP(const u32* p) {
  return __hip_atomic_load(p, __ATOMIC_RELAXED, __HIP_MEMORY_SCOPE_AGENT);
}
__device__ __forceinline__ void stW(u32* p, u32 v) {
  __hip_atomic_store(p, v, __ATOMIC_RELAXED, __HIP_MEMORY_SCOPE_AGENT);
}
__device__ __forceinline__ u32 ldW(const u32* p) {
  return __hip_atomic_load(p, __ATOMIC_RELAXED, __HIP_MEMORY_SCOPE_AGENT);
}

// Flag layout: replicated private lines, flags[(slot*64 + consumerBlk)*32].
// Hot spin, wave-0-only poll, raw s_barrier release. (R3 wiring — proven.)
__device__ __forceinline__ void waitP(u32* flags, int baseA, int na, u32 thA,
                                      int baseB, int nbb, u32 thB,
                                      int baseS, int ns, u32 thS) {
  const int tid = threadIdx.x;
  const int rep = blockIdx.x;
  if (tid < 64) {
    for (;;) {
      int ok = 1;
      if (tid < na) ok = (ldP(&flags[((baseA + tid) * 64 + rep) * 32]) >= thA) ? 1 : 0;
      else if (tid < na + nbb) ok = (ldP(&flags[((baseB + tid - na) * 64 + rep) * 32]) >= thB) ? 1 : 0;
      else if (tid < na + nbb + ns) ok = (ldP(&flags[((baseS + tid - na - nbb) * 64 + rep) * 32]) >= thS) ? 1 : 0;
      if (__all(ok)) break;
    }
  }
  bar0();
}

// ---------------- fabric/uncore heater (blocks 54..255), SAFE build --------
// R4 falsified SHADER-clock DVFS (FMA heaters: null). The uniform ~6-10x
// inflation of every memory-LATENCY estimate (while compute throughput
// matches the cycle model exactly) points at the FABRIC/LLC clock domain
// idling at minimum DPM (~1% memory util). R7's streaming heater crashed in
// unexplainable machinery; this rebuild uses ONLY the ldP primitive (the
// exact relaxed-agent atomic load the pollers have run billions of times):
// 2 loads/lane/iter over an 8MB LLC-resident scratch, 128B-spaced lines,
// paced by ~1000 dependent FMAs -> ~10 GB/s/block, ~2 TB/s aggregate pure
// LLC/fabric read traffic, ~zero HBM. Exit: poll L6 done-flag (R4 wiring).
__device__ __attribute__((noinline)) void heater_mem(u32* flags, u32 target,
                                                     u32* scratch) {
  if (threadIdx.x >= 64) return;  // 1 wave per heater CU
  const u32* done = &flags[(53 * 64 + 54) * 32];
  const u32 mask = 0x1FFFFFu;     // 2M words = 8MB; all offsets multiple of 32 words (128B)
  u32 base = ((u32)blockIdx.x * 8192u + (u32)threadIdx.x * 32u) & mask;
  u32 sink = 0;
  float a = 1.0f + (float)threadIdx.x;
  for (;;) {
    sink ^= ldP(scratch + base);
    sink ^= ldP(scratch + ((base + 2048u) & mask));
    // pacing: ~1000 dependent FMAs (~1.7us) so aggregate stays ~2 TB/s
    for (int i = 0; i < 1000; ++i) a = __builtin_fmaf(a, 1.0000001f, 1e-30f);
    asm volatile("" :: "v"(sink), "v"(a));
    base = (base + 8192u) & mask;
    if (ldP(done) >= target) break;
  }
}

// ---------------- x -> bf16 cast ----------------
__global__ __launch_bounds__(256) void cast_bf16(const float* __restrict__ in,
                                                 u16* __restrict__ outp, int n4) {
  int i = blockIdx.x * 256 + threadIdx.x;
  if (i < n4) {
    float4 v = *(const float4*)(in + (size_t)i * 4);
    u16 o[4] = {(u16)f2b(v.x), (u16)f2b(v.y), (u16)f2b(v.z), (u16)f2b(v.w)};
    *(u64*)(outp + (size_t)i * 4) = *(const u64*)o;
  }
}

// ---------------- weight -> MFMA B-fragment order (L1 rec + L1 gemm) ----------------
__global__ __launch_bounds__(256) void prep_frags(const float* __restrict__ src,
                                                  u16* __restrict__ dst,
                                                  int N, int Ksrc, int Ks,
                                                  int JT, int U, int recmode, int total_fid) {
  int t = blockIdx.x * 256 + threadIdx.x;
  int lane = t & 63, fid = t >> 6;
  if (fid >= total_fid) return;
  int l15 = lane & 15, quad = lane >> 4;
  int ks = fid % Ks;
  int n, valid_n;
  if (recmode) {
    int rest = fid / Ks;
    int jt = rest % JT;
    int g = rest / JT;
    int jj = jt * 16 + l15;
    n = g * U + jj;
    valid_n = (jj < U) ? 1 : 0;
  } else {
    int nt = fid / Ks;
    n = nt * 16 + l15;
    valid_n = (n < N) ? 1 : 0;
  }
  u16* o = dst + ((size_t)fid * 64 + lane) * 8;
#pragma unroll
  for (int j = 0; j < 8; ++j) {
    int k = ks * 32 + quad * 8 + j;
    float v = (valid_n && k < Ksrc) ? src[(size_t)k * N + n] : 0.f;
    o[j] = (u16)f2b(v);
  }
}

// ---------------- combined [K-input | K-input2 | R] fragged weights (stages 2..6) -----
__global__ __launch_bounds__(256) void prep_comb(const float* __restrict__ Kmat,
                                                 const float* __restrict__ Rmat,
                                                 u16* __restrict__ dst,
                                                 int N, int U, int w1v, int w1p,
                                                 int w2v, int w2p, int Ks, int JT,
                                                 int total_fid) {
  int t = blockIdx.x * 256 + threadIdx.x;
  int lane = t & 63, fid = t >> 6;
  if (fid >= total_fid) return;
  int l15 = lane & 15, quad = lane >> 4;
  int ks = fid % Ks;
  int rest = fid / Ks;
  int jt = rest % JT;
  int g = rest / JT;
  int j = jt * 16 + l15;
  bool jv = (j < U);
  int n = g * U + (jv ? j : 0);
  u16* o = dst + ((size_t)fid * 64 + lane) * 8;
#pragma unroll
  for (int jj = 0; jj < 8; ++jj) {
    int k = ks * 32 + quad * 8 + jj;
    float v = 0.f;
    if (jv) {
      if (k < w1p) {
        if (k < w1v) v = Kmat[(size_t)k * N + n];
      } else if (k < w1p + w2p) {
        int kr = k - w1p;
        if (kr < w2v) v = Kmat[(size_t)(w1v + kr) * N + n];
      } else {
        int rr = k - w1p - w2p;
        if (rr < U) v = Rmat[(size_t)rr * N + n];
      }
    }
    o[jj] = (u16)f2b(v);
  }
}

// ---------------- MFMA GEMM (L1 xp only): C[M,3072] = A[M,512]bf16 @ W + bias -------
__global__ __launch_bounds__(256) void gemm_mfma(const u16* __restrict__ A, int strideA, int Kact,
                                                 const u16* __restrict__ Bf,
                                                 const float* __restrict__ bias,
                                                 float* __restrict__ C,
                                                 int N, int Ntiles, int Ks,
                                                 int t0, int tcLog2) {
  __shared__ char sha[16 * 2056];
  const int tid = threadIdx.x;
  const int lane = tid & 63, l15 = lane & 15, quad = lane >> 4, w = tid >> 6;
  const int KS4 = Ks * 8;
  const int rowB = Ks * 64 + 8;
  const int bm = blockIdx.y * 16;

  for (int i = tid; i < 16 * KS4; i += 256) {
    int r = i / KS4, u = i - r * KS4;
    u64 v = 0;
    if (u * 4 < Kact) {
      int rl = bm + r;
      size_t grow;
      if (t0 >= 0) {
        int tcm = (1 << tcLog2) - 1;
        grow = (((size_t)(rl >> tcLog2)) << 9) + t0 + (rl & tcm);
      } else {
        grow = (size_t)rl;
      }
      v = *((const u64*)(A + grow * (size_t)strideA) + u);
    }
    *(u64*)(sha + r * rowB + u * 8) = v;
  }
  __syncthreads();

  f4v acc[4];
  f4v z4 = {0.f, 0.f, 0.f, 0.f};
#pragma unroll
  for (int q = 0; q < 4; ++q) acc[q] = z4;

  const int ntb = blockIdx.x * 16 + w * 4;
  for (int ks = 0; ks < Ks; ++ks) {
    int off = l15 * rowB + ks * 64 + quad * 16;
    s8v a = *(const s8v*)(sha + off);
#pragma unroll
    for (int q = 0; q < 4; ++q) {
      int nt = ntb + q;
      if (nt < Ntiles) {
        s8v b = *(const s8v*)(Bf + (((size_t)nt * Ks + ks) * 64 + lane) * 8);
        acc[q] = __builtin_amdgcn_mfma_f32_16x16x32_bf16(a, b, acc[q], 0, 0, 0);
      }
    }
  }
#pragma unroll
  for (int q = 0; q < 4; ++q) {
    int nt = ntb + q;
    if (nt >= Ntiles) continue;
    int col = nt * 16 + l15;
    if (col < N) {
      float bv = bias[col];
#pragma unroll
      for (int r = 0; r < 4; ++r) {
        int rowl = bm + quad * 4 + r;
        C[(size_t)rowl * N + col] = acc[q][r] + bv;
      }
    }
  }
}

// ---------------- generic stage config ----------------
struct GCfg {
  const u16 *s1, *s2;        // input row-buffers [row][w?p] bf16
  const u16* Bf;             // combined fragged weights
  const float* bias;         // [2][3U]
  u16* ydst;                 // bf16 out rows [row][Upad] (or null)
  float* fdst;               // fp32 out (or null)
  u16* hglob;                // nb>1: [2][32][Upad] LLC; nb==1: hsave [32][Upad]
  int w1p, w2p, Upad, U, Ks, ksIn, JT, nb, base, act, wfd;
  int baseA, na, baseB, nbb; // producer flag polls (>= t+1)
  int pubF, pubN;            // flag replica publish range: consumers pubF..pubF+pubN-1
};

// LDS map: L1 path: h tile [32 rows][2048B +16 pad] = 66048, then K-split
// partial-sum area 3 gates x 12 waves x 64 lanes x 16B = 36864.
// stage_gen path: Ab [0..74240), Hp [74240..) (nb==1 stages, Upad=32 only).
#define REDOFF 66048
#define SMEM_BYTES 102912
#define HPOFF 74240

// ---------------- stage L1: 32 blocks x 1024 thr ----------------------------
__device__ __attribute__((noinline)) void stage_l1(
    const float* xp, const u16* Bf, const float* brec, u16* hbuf, u16* yout,
    u32* flags, int t0, int tc, char* smem) {
  const int tid = threadIdx.x;
  const int lane = tid & 63, l15 = lane & 15, quad = (lane >> 4) & 3;
  const int w = tid >> 6;             // 0..15
  const int kq = w >> 2;              // 0..3 : ks range [kq*8, kq*8+8)
  const int jt_l = (w >> 1) & 1;
  const int Mt = w & 1;
  const int blk = blockIdx.x;         // 0..31
  const int jt = blk * 2 + jt_l;
  const int j = jt * 16 + l15;
  const int HP = 32 * 1024;
  const bool own = (kq == 0);

  float bz = 0.f, brr = 0.f, bh = 0.f;
  float hprev[4];
  if (own) {
    bz = brec[j]; brr = brec[1024 + j]; bh = brec[2048 + j];
    const u32* hp = (const u32*)(hbuf + (size_t)(t0 & 1) * HP);
#pragma unroll
    for (int r = 0; r < 4; ++r) {
      int b = Mt * 16 + quad * 4 + r;
      u32 wd = ldW(hp + ((b * 1024 + (j & ~1)) >> 1));
      hprev[r] = b2f((j & 1) ? (u16)(wd >> 16) : (u16)(wd & 0xffff));
    }
  }

  for (int tt = 0; tt < tc; ++tt) {
    const int t = t0 + tt;
    waitP(flags, 0, 32, (u32)t, 0, 0, 0, 0, 0, 0);
    // xp NT loads first (longest latency); they stay in flight across the
    // lean barriers below and are consumed in the epilogue.
    float xv[3][4];
    if (own) {
#pragma unroll
      for (int r = 0; r < 4; ++r) {
        int b = Mt * 16 + quad * 4 + r;
        const float* xr_ = xp + ((size_t)b * tc + tt) * 3072;
        xv[0][r] = __builtin_nontemporal_load(xr_ + j);
        xv[1][r] = __builtin_nontemporal_load(xr_ + 1024 + j);
        xv[2][r] = __builtin_nontemporal_load(xr_ + 2048 + j);
      }
    }
    // stage h -> LDS: 4096x16B over 1024 threads = 4 pipelined loads
    {
      const char* hsrc = (const char*)(hbuf + (size_t)(t & 1) * HP);
      f4v vals[4];
#pragma unroll
      for (int i = 0; i < 4; ++i)
        vals[i] = load16_sc(hsrc + (size_t)(tid + i * 1024) * 16);
      vm_wait0();
#pragma unroll
      for (int i = 0; i < 4; ++i) {
        int g16 = tid + i * 1024;
        *(f4v*)(smem + (g16 >> 7) * 2064 + (g16 & 127) * 16) = vals[i];
      }
    }
    bar_lgkm();   // staging visible; xp/B loads NOT drained
    f4v acc[3];
    f4v z4 = {0.f, 0.f, 0.f, 0.f};
#pragma unroll
    for (int g = 0; g < 3; ++g) acc[g] = z4;
#pragma unroll
    for (int i = 0; i < 8; ++i) {
      int ks = kq * 8 + i;
      s8v a = *(const s8v*)(smem + (Mt * 16 + l15) * 2064 + ks * 64 + quad * 16);
#pragma unroll
      for (int g = 0; g < 3; ++g) {
        s8v b = *(const s8v*)(Bf + (((size_t)(g * 64 + jt) * 32 + ks) * 64 + lane) * 8);
        acc[g] = __builtin_amdgcn_mfma_f32_16x16x32_bf16(a, b, acc[g], 0, 0, 0);
      }
    }
    if (!own) {
      int idx = (kq - 1) * 4 + (w & 3);
#pragma unroll
      for (int g = 0; g < 3; ++g)
        *(f4v*)(smem + REDOFF + ((g * 12 + idx) * 64 + lane) * 16) = acc[g];
    }
    bar_lgkm();   // partials visible; vmcnt untouched
    if (own) {
#pragma unroll
      for (int g = 0; g < 3; ++g)
#pragma unroll
        for (int kk = 0; kk < 3; ++kk) {
          f4v p = *(const f4v*)(smem + REDOFF + ((g * 12 + kk * 4 + w) * 64 + lane) * 16);
          acc[g] += p;
        }
      u16* hdst = hbuf + (size_t)((t + 1) & 1) * HP;
#pragma unroll
      for (int r = 0; r < 4; ++r) {
        int b = Mt * 16 + quad * 4 + r;
        size_t row = (size_t)b * tc + tt;
        float z = sigm(xv[0][r] + acc[0][r] + bz);
        float rr = sigm(xv[1][r] + acc[1][r] + brr);
        float hh = fmaxf(xv[2][r] + rr * (acc[2][r] + bh), 0.f);
        float hnew = z * hprev[r] + (1.f - z) * hh;
        hprev[r] = hnew;
        float part = __shfl_xor(hnew, 1, 64);
        if ((l15 & 1) == 0) {
          u32 wd = (u32)(u16)f2b(hnew) | ((u32)(u16)f2b(part) << 16);
          stW((u32*)hdst + ((b * 1024 + j) >> 1), wd);
          stW((u32*)yout + ((row * 1024 + j) >> 1), wd);
        }
      }
      vm_wait0();  // only owner waves have data stores to drain
    }
    bar0();        // all owners drained -> publish is a valid release
    // publish: one scatter store, lane -> consumer block replica.
    if (tid < 40) stW(&flags[(blk * 64 + tid) * 32], (u32)(t + 1));
  }
}

// ---------------- generic fused stage (L2..L6), 1024 threads ----------------
__device__ __attribute__((noinline)) void stage_gen(
    const GCfg& c, int bs, u32* flags, int t0, int tc, int initH, char* smem) {
  const int tid = threadIdx.x;
  const int lane = tid & 63, l15 = lane & 15, quad = (lane >> 4) & 3;
  const int w = tid >> 6;  // 0..15
  const int Kc = c.w1p + c.w2p + c.Upad;
  const int rowA = Kc * 2 + 16;
  const int rowH = c.Upad * 2 + 16;
  char* Ab = smem;
  char* Hp = smem + HPOFF;
  const int HB = 32 * rowH;
  const int uIn = (c.w1p + c.w2p) >> 3;
  const int uH = c.Upad >> 3;
  const int upr = uIn + ((c.nb > 1) ? uH : 0);
  const int total_units = 32 * upr;
  const int u1 = c.w1p >> 3;
  const int U = c.U;
  const int HPstride = 32 * c.Upad;

  const int ntask = c.JT * 2;
  int tcount = 0;
  int tjt[2], tmt[2];
#pragma unroll
  for (int i = 0; i < 2; ++i) {
    int task = w * c.nb + bs + i * 16 * c.nb;
    if (task < ntask) { tjt[tcount] = task >> 1; tmt[tcount] = task & 1; ++tcount; }
  }

  const float* b0 = c.bias;
  const float* b1 = c.bias + 3 * U;
  float bz[2], br_[2], bih[2], brh[2];
  int jl[2];
  bool jv[2];
#pragma unroll
  for (int i = 0; i < 2; ++i) {
    if (i >= tcount) { jv[i] = false; jl[i] = 0; bz[i] = br_[i] = bih[i] = brh[i] = 0.f; continue; }
    int j = tjt[i] * 16 + l15;
    jv[i] = (j < U);
    int jc = jv[i] ? j : 0;
    jl[i] = j;
    bz[i] = b0[jc] + b1[jc];
    br_[i] = b0[U + jc] + b1[U + jc];
    bih[i] = b0[2 * U + jc];
    brh[i] = b1[2 * U + jc];
  }

  if (c.nb == 1) {
    for (int i = tid; i < (2 * HB) >> 2; i += 1024) ((u32*)Hp)[i] = 0;
    __syncthreads();
    if (!initH) {
      for (int i = tid; i < 32 * uH; i += 1024) {
        int m = i / uH, u = i - m * uH;
        *(f4v*)(Hp + (t0 & 1) * HB + m * rowH + u * 16) = *((const f4v*)c.hglob + i);
      }
    }
    __syncthreads();
  }

  float hprev[2][4];
#pragma unroll
  for (int i = 0; i < 2; ++i) {
    if (i >= tcount) continue;
#pragma unroll
    for (int r = 0; r < 4; ++r) {
      int b = tmt[i] * 16 + quad * 4 + r;
      float hv;
      if (c.nb > 1) {
        u32 wd = ldW((const u32*)c.hglob + (((t0 & 1) * HPstride + b * c.Upad + (jl[i] & ~1)) >> 1));
        hv = b2f((jl[i] & 1) ? (u16)(wd >> 16) : (u16)(wd & 0xffff));
      } else {
        hv = b2f(*(const u16*)(Hp + (t0 & 1) * HB + b * rowH + jl[i] * 2));
      }
      hprev[i][r] = jv[i] ? hv : 0.f;
    }
  }

  for (int tt = 0; tt < tc; ++tt) {
    const int t = t0 + tt;
    waitP(flags, c.baseA, c.na, (u32)(t + 1), c.baseB, c.nbb, (u32)(t + 1),
          c.base, (c.nb > 1) ? c.nb : 0, (u32)t);
    // ---- stage A (inputs [+h if nb>1]) into LDS ----
    {
      f4v vals[5];
      int offs[5];
#pragma unroll
      for (int i = 0; i < 5; ++i) {
        int idx = tid + i * 1024;
        int pidx = (idx < total_units) ? idx : (total_units - 1);
        int m = pidx / upr, u = pidx - m * upr;
        const char* src;
        if (u < u1)
          src = (const char*)c.s1 + ((size_t)(m * tc + tt) * c.w1p + (u << 3)) * 2;
        else if (u < uIn)
          src = (const char*)c.s2 + ((size_t)(m * tc + tt) * c.w2p + ((u - u1) << 3)) * 2;
        else
          src = (const char*)c.hglob + ((size_t)(t & 1) * HPstride + m * c.Upad + ((u - uIn) << 3)) * 2;
        vals[i] = load16_sc(src);
        offs[i] = m * rowA + u * 16;
      }
      vm_wait0();
#pragma unroll
      for (int i = 0; i < 5; ++i)
        if (tid + i * 1024 < total_units) *(f4v*)(Ab + offs[i]) = vals[i];
    }
    bar_lgkm();   // staging visible; B-fragment loads keep flowing
    // ---- MFMA: input-K part (z,r,xh), then h part (z,r,rh) ----
    f4v az[2], ar[2], axh[2], arh[2];
    f4v z4 = {0.f, 0.f, 0.f, 0.f};
#pragma unroll
    for (int i = 0; i < 2; ++i) { az[i] = z4; ar[i] = z4; axh[i] = z4; arh[i] = z4; }
    for (int ks = 0; ks < c.ksIn; ++ks) {
#pragma unroll
      for (int i = 0; i < 2; ++i) {
        if (i >= tcount) break;
        s8v a = *(const s8v*)(Ab + (tmt[i] * 16 + l15) * rowA + ks * 64 + quad * 16);
        const u16* bb = c.Bf + ((size_t)tjt[i] * c.Ks + ks) * 512 + lane * 8;
        s8v bz_ = *(const s8v*)(bb);
        s8v br2 = *(const s8v*)(bb + (size_t)c.JT * c.Ks * 512);
        s8v bh2 = *(const s8v*)(bb + (size_t)2 * c.JT * c.Ks * 512);
        az[i] = __builtin_amdgcn_mfma_f32_16x16x32_bf16(a, bz_, az[i], 0, 0, 0);
        ar[i] = __builtin_amdgcn_mfma_f32_16x16x32_bf16(a, br2, ar[i], 0, 0, 0);
        axh[i] = __builtin_amdgcn_mfma_f32_16x16x32_bf16(a, bh2, axh[i], 0, 0, 0);
      }
    }
    for (int ks = c.ksIn; ks < c.Ks; ++ks) {
#pragma unroll
      for (int i = 0; i < 2; ++i) {
        if (i >= tcount) break;
        s8v a;
        if (c.nb > 1)
          a = *(const s8v*)(Ab + (tmt[i] * 16 + l15) * rowA + ks * 64 + quad * 16);
        else
          a = *(const s8v*)(Hp + (t & 1) * HB + (tmt[i] * 16 + l15) * rowH + (ks - c.ksIn) * 64 + quad * 16);
        const u16* bb = c.Bf + ((size_t)tjt[i] * c.Ks + ks) * 512 + lane * 8;
        s8v bz_ = *(const s8v*)(bb);
        s8v br2 = *(const s8v*)(bb + (size_t)c.JT * c.Ks * 512);
        s8v bh2 = *(const s8v*)(bb + (size_t)2 * c.JT * c.Ks * 512);
        az[i] = __builtin_amdgcn_mfma_f32_16x16x32_bf16(a, bz_, az[i], 0, 0, 0);
        ar[i] = __builtin_amdgcn_mfma_f32_16x16x32_bf16(a, br2, ar[i], 0, 0, 0);
        arh[i] = __builtin_amdgcn_mfma_f32_16x16x32_bf16(a, bh2, arh[i], 0, 0, 0);
      }
    }
    // ---- gates + publish ----
#pragma unroll
    for (int i = 0; i < 2; ++i) {
      if (i >= tcount) break;
#pragma unroll
      for (int r = 0; r < 4; ++r) {
        int b = tmt[i] * 16 + quad * 4 + r;
        size_t row = (size_t)b * tc + tt;
        float z = sigm(az[i][r] + bz[i]);
        float rg = sigm(ar[i][r] + br_[i]);
        float hh = axh[i][r] + bih[i] + rg * (arh[i][r] + brh[i]);
        if (c.act) hh = fmaxf(hh, 0.f);
        float hnew = z * hprev[i][r] + (1.f - z) * hh;
        if (!jv[i]) hnew = 0.f;
        hprev[i][r] = hnew;
        int j = jl[i];
        float part = __shfl_xor(hnew, 1, 64);
        u32 wd = (u32)(u16)f2b(hnew) | ((u32)(u16)f2b(part) << 16);
        if ((l15 & 1) == 0) {
          if (c.ydst) stW((u32*)c.ydst + ((row * c.Upad + j) >> 1), wd);
          if (c.nb > 1)
            stW((u32*)c.hglob + ((((t + 1) & 1) * HPstride + b * c.Upad + j) >> 1), wd);
        }
        if (c.nb == 1) *(u16*)(Hp + ((t + 1) & 1) * HB + b * rowH + j * 2) = (u16)f2b(hnew);
        if (c.fdst && jv[i] && j < c.wfd)
          c.fdst[((size_t)b * TT + t) * c.wfd + j] = hnew;
      }
    }
    vm_wait0();   // cheap for non-store waves (their loads drained at staging)
    bar0();       // all data stores drained -> publish is a valid release
    if (tid < c.pubN)
      stW(&flags[((c.base + bs) * 64 + c.pubF + tid) * 32], (u32)(t + 1));
  }
  if (c.nb == 1) {
    int pf = (t0 + tc) & 1;
    for (int i = tid; i < 32 * uH; i += 1024) {
      int m = i / uH, u = i - m * uH;
      *((f4v*)c.hglob + i) = *(const f4v*)(Hp + pf * HB + m * rowH + u * 16);
    }
  }
}

// ---------------- the pipeline kernel: 256 blocks x 1024 ----------------
// slots: L1=0..31, L2=32..39, L3=40, L4=41..48, L5=49..52, L6=53, heaters 54+
__global__ __launch_bounds__(1024, 1) void pipeline(
    const float* xp, const u16* BfL1, const float* brecL1, u16* hbufL1, u16* y1c,
    u32* heatscratch,
    GCfg c1, GCfg c2, GCfg c3, GCfg c4, GCfg c5,
    u32* flags, int t0, int tc, int initH) {
  __shared__ char smem[SMEM_BYTES];
  int blk = blockIdx.x;
  if (blk < 32) stage_l1(xp, BfL1, brecL1, hbufL1, y1c, flags, t0, tc, smem);
  else if (blk < 40) stage_gen(c1, blk - 32, flags, t0, tc, initH, smem);
  else if (blk < 41) stage_gen(c2, 0, flags, t0, tc, initH, smem);
  else if (blk < 49) stage_gen(c3, blk - 41, flags, t0, tc, initH, smem);
  else if (blk < 53) stage_gen(c4, blk - 49, flags, t0, tc, initH, smem);
  else if (blk < 54) stage_gen(c5, 0, flags, t0, tc, initH, smem);
  else heater_mem(flags, (u32)(t0 + tc), heatscratch);
}

// ---------------- host launch ----------------
extern "C" void kernel_launch(void* const* d_in, const int* in_sizes, int n_in,
                              void* d_out, int out_size, void* d_ws, size_t ws_size,
                              hipStream_t stream) {
  const float* x = (const float*)d_in[0];

  int tcLog2 = 6;
  {
    size_t fixed = (size_t)16384 * 512 * 2
                   + (3145728ull + 1572864ull + 442368 + 15360 + 319488 + 147456 + 7680) * 2
                   + 8388608 + 900000;
    for (; tcLog2 >= 4; --tcLog2) {
      size_t rc = (size_t)BB << tcLog2;
      size_t per = rc * 3072 * 4 + rc * (1024 + 128 + 32 + 256 + 128) * 2 + 8192;
      if (fixed + per <= ws_size || tcLog2 == 4) break;
    }
  }
  const int Tc = 1 << tcLog2;
  const int NCk = TT / Tc;
  const size_t RC = (size_t)BB * Tc;

  char* ws = (char*)d_ws;
  size_t off = 0;
  auto alloc = [&](size_t bytes) -> char* {
    char* p = ws + off;
    off += (bytes + 255) & ~(size_t)255;
    return p;
  };

  u32* flags = (u32*)alloc((size_t)54 * 64 * 32 * sizeof(u32));
  u16* hbufL1 = (u16*)alloc((size_t)2 * 32 * 1024 * 2);
  u16* hb2 = (u16*)alloc((size_t)2 * 32 * 128 * 2);
  u16* hb4 = (u16*)alloc((size_t)2 * 32 * 256 * 2);
  u16* hb5 = (u16*)alloc((size_t)2 * 32 * 128 * 2);
  u16* hs3 = (u16*)alloc((size_t)32 * 32 * 2);
  u16* hs6 = (u16*)alloc((size_t)32 * 32 * 2);
  u16* recB1 = (u16*)alloc(3145728ull * 2);
  u16* gemB1 = (u16*)alloc(1572864ull * 2);
  u16* cB[5];
  const size_t cBe[5] = {442368, 15360, 319488, 147456, 7680};
  for (int i = 0; i < 5; ++i) cB[i] = (u16*)alloc(cBe[i] * 2);
  u16* x16 = (u16*)alloc((size_t)16384 * 512 * 2);
  u32* heatscratch = (u32*)alloc(8388608);  // 8MB LLC-resident heater region
  float* xp = (float*)alloc(RC * 3072 * sizeof(float));
  u16* y1c = (u16*)alloc(RC * 1024 * 2);
  u16* y2c = (u16*)alloc(RC * 128 * 2);
  u16* yec = (u16*)alloc(RC * 32 * 2);
  u16* y4c = (u16*)alloc(RC * 256 * 2);
  u16* y5c = (u16*)alloc(RC * 128 * 2);

  float* outye = (float*)d_out;
  float* outyd = outye + (size_t)BB * TT * 23;

  hipMemsetAsync(flags, 0, (size_t)54 * 64 * 32 * sizeof(u32), stream);
  hipMemsetAsync(hbufL1, 0, (size_t)2 * 32 * 1024 * 2, stream);
  hipMemsetAsync(hb2, 0, (size_t)2 * 32 * 128 * 2, stream);
  hipMemsetAsync(hb4, 0, (size_t)2 * 32 * 256 * 2, stream);
  hipMemsetAsync(hb5, 0, (size_t)2 * 32 * 128 * 2, stream);

  {
    int n4 = (16384 * 512) / 4;
    hipLaunchKernelGGL(cast_bf16, dim3((n4 + 255) / 256), dim3(256), 0, stream, x, x16, n4);
    hipLaunchKernelGGL(prep_frags, dim3((3 * 64 * 32 * 64 + 255) / 256), dim3(256), 0, stream,
                       (const float*)d_in[2], recB1, 3072, 1024, 32, 64, 1024, 1, 3 * 64 * 32);
    hipLaunchKernelGGL(prep_frags, dim3((192 * 16 * 64 + 255) / 256), dim3(256), 0, stream,
                       (const float*)d_in[1], gemB1, 3072, 512, 16, 0, 0, 0, 192 * 16);
    const int pc[5][8] = {
        {384, 128, 1024, 1024, 0, 0, 36, 8},   // L2
        {69, 23, 128, 128, 0, 0, 5, 2},        // L3
        {768, 256, 128, 128, 23, 32, 13, 16},  // L4
        {384, 128, 256, 256, 0, 0, 12, 8},     // L5
        {24, 8, 128, 128, 0, 0, 5, 1}};        // L6
    for (int i = 0; i < 5; ++i) {
      int l = i + 1;
      int tf = 3 * pc[i][7] * pc[i][6];
      hipLaunchKernelGGL(prep_comb, dim3((tf * 64 + 255) / 256), dim3(256), 0, stream,
                         (const float*)d_in[1 + 3 * l], (const float*)d_in[2 + 3 * l], cB[i],
                         pc[i][0], pc[i][1], pc[i][2], pc[i][3], pc[i][4], pc[i][5],
                         pc[i][6], pc[i][7], tf);
    }
  }

  // slots: L1=0..31, L2=32..39, L3=40, L4=41..48, L5=49..52, L6=53
  // pub ranges: L1->consumers 0..39 (hardcoded in stage_l1);
  // L2(32..39)->32..48; L3(40)->41..48; L4(41..48)->41..52; L5(49..52)->49..53;
  // L6(53)->54 (heater done-flag, R4-proven wiring).
  GCfg c1 = {y1c, nullptr, cB[0], (const float*)d_in[6], y2c, nullptr, hb2,
             1024, 0, 128, 128, 36, 32, 8, 8, 32, 1, 0, 0, 32, 0, 0, 32, 17};
  GCfg c2 = {y2c, nullptr, cB[1], (const float*)d_in[9], yec, outye, hs3,
             128, 0, 32, 23, 5, 4, 2, 1, 40, 0, 23, 32, 8, 0, 0, 41, 8};
  GCfg c3 = {y2c, yec, cB[2], (const float*)d_in[12], y4c, nullptr, hb4,
             128, 32, 256, 256, 13, 5, 16, 8, 41, 1, 0, 32, 8, 40, 1, 41, 12};
  GCfg c4 = {y4c, nullptr, cB[3], (const float*)d_in[15], y5c, nullptr, hb5,
             256, 0, 128, 128, 12, 8, 8, 4, 49, 1, 0, 41, 8, 0, 0, 49, 5};
  GCfg c5 = {y5c, nullptr, cB[4], (const float*)d_in[18], nullptr, outyd, hs6,
             128, 0, 32, 8, 5, 4, 1, 1, 53, 0, 8, 49, 4, 0, 0, 54, 1};

  const float* biasL1 = (const float*)d_in[3];

  for (int c = 0; c < NCk; ++c) {
    const int t0 = c * Tc;
    hipLaunchKernelGGL(gemm_mfma, dim3(12, (unsigned)(RC / 16)), dim3(256), 0, stream,
                       x16, 512, 512, gemB1, biasL1, xp, 3072, 192, 16, t0, tcLog2);
    hipLaunchKernelGGL(pipeline, dim3(256), dim3(1024), 0, stream,
                       xp, recB1, biasL1 + 3072, hbufL1, y1c, heatscratch,
                       c1, c2, c3, c4, c5, flags, t0, Tc, (c == 0) ? 1 : 0);
  }
}

// Round 10
// 13528.925 us; speedup vs baseline: 1.6670x; 1.6670x over previous
//
#include <hip/hip_runtime.h>
#include <hip/hip_bf16.h>
#include <cstdint>
#include <cstddef>

#define BB 32
#define TT 512

typedef short s8v __attribute__((ext_vector_type(8)));
typedef float f4v __attribute__((ext_vector_type(4)));
typedef unsigned long long u64;
typedef unsigned short u16;
typedef unsigned int u32;

__device__ __forceinline__ short f2b(float x) {
  __hip_bfloat16 h = __float2bfloat16(x);
  return *reinterpret_cast<short*>(&h);
}
__device__ __forceinline__ float b2f(u16 x) {
  __hip_bfloat16 h = *reinterpret_cast<__hip_bfloat16*>(&x);
  return __bfloat162float(h);
}
__device__ __forceinline__ float sigm(float x) { return 1.f / (1.f + __expf(-x)); }

// LLC-coherent pipelined 16B load; caller must vm_wait0() before use.
__device__ __forceinline__ f4v load16_sc(const void* p) {
  f4v v;
  asm volatile("global_load_dwordx4 %0, %1, off sc0 sc1" : "=v"(v) : "v"(p));
  return v;
}
__device__ __forceinline__ void vm_wait0() {
  asm volatile("s_waitcnt vmcnt(0)" ::: "memory");
}
// Lean barriers: raw s_barrier with ONLY the counter correctness needs.
// (R3-proven: __syncthreads' full vmcnt+lgkm drain is replaced by targeted
// waits; B-fragment / xp loads stay in flight across barriers.)
__device__ __forceinline__ void bar0() {
  asm volatile("" ::: "memory");
  __builtin_amdgcn_s_barrier();
  asm volatile("" ::: "memory");
}
__device__ __forceinline__ void bar_lgkm() {
  asm volatile("s_waitcnt lgkmcnt(0)" ::: "memory");
  __builtin_amdgcn_s_barrier();
  asm volatile("" ::: "memory");
}
__device__ __forceinline__ u32 ldP(const u32* p) {
  return __hip_atomic_load(p, __ATOMIC_RELAXED, __HIP_MEMORY_SCOPE_AGENT);
}
__device__ __forceinline__ void stW(u32* p, u32 v) {
  __hip_atomic_store(p, v, __ATOMIC_RELAXED, __HIP_MEMORY_SCOPE_AGENT);
}
__device__ __forceinline__ u32 ldW(const u32* p) {
  return __hip_atomic_load(p, __ATOMIC_RELAXED, __HIP_MEMORY_SCOPE_AGENT);
}

// Flag layout: replicated private lines, flags[(slot*64 + consumerBlk)*32].
// Hot spin, wave-0-only poll, raw s_barrier release. (R3 wiring — proven best.)
__device__ __forceinline__ void waitP(u32* flags, int baseA, int na, u32 thA,
                                      int baseB, int nbb, u32 thB,
                                      int baseS, int ns, u32 thS) {
  const int tid = threadIdx.x;
  const int rep = blockIdx.x;
  if (tid < 64) {
    for (;;) {
      int ok = 1;
      if (tid < na) ok = (ldP(&flags[((baseA + tid) * 64 + rep) * 32]) >= thA) ? 1 : 0;
      else if (tid < na + nbb) ok = (ldP(&flags[((baseB + tid - na) * 64 + rep) * 32]) >= thB) ? 1 : 0;
      else if (tid < na + nbb + ns) ok = (ldP(&flags[((baseS + tid - na - nbb) * 64 + rep) * 32]) >= thS) ? 1 : 0;
      if (__all(ok)) break;
    }
  }
  bar0();
}

// ---------------- x -> bf16 cast ----------------
__global__ __launch_bounds__(256) void cast_bf16(const float* __restrict__ in,
                                                 u16* __restrict__ outp, int n4) {
  int i = blockIdx.x * 256 + threadIdx.x;
  if (i < n4) {
    float4 v = *(const float4*)(in + (size_t)i * 4);
    u16 o[4] = {(u16)f2b(v.x), (u16)f2b(v.y), (u16)f2b(v.z), (u16)f2b(v.w)};
    *(u64*)(outp + (size_t)i * 4) = *(const u64*)o;
  }
}

// ---------------- weight -> MFMA B-fragment order (L1 rec + L1 gemm) ----------------
__global__ __launch_bounds__(256) void prep_frags(const float* __restrict__ src,
                                                  u16* __restrict__ dst,
                                                  int N, int Ksrc, int Ks,
                                                  int JT, int U, int recmode, int total_fid) {
  int t = blockIdx.x * 256 + threadIdx.x;
  int lane = t & 63, fid = t >> 6;
  if (fid >= total_fid) return;
  int l15 = lane & 15, quad = lane >> 4;
  int ks = fid % Ks;
  int n, valid_n;
  if (recmode) {
    int rest = fid / Ks;
    int jt = rest % JT;
    int g = rest / JT;
    int jj = jt * 16 + l15;
    n = g * U + jj;
    valid_n = (jj < U) ? 1 : 0;
  } else {
    int nt = fid / Ks;
    n = nt * 16 + l15;
    valid_n = (n < N) ? 1 : 0;
  }
  u16* o = dst + ((size_t)fid * 64 + lane) * 8;
#pragma unroll
  for (int j = 0; j < 8; ++j) {
    int k = ks * 32 + quad * 8 + j;
    float v = (valid_n && k < Ksrc) ? src[(size_t)k * N + n] : 0.f;
    o[j] = (u16)f2b(v);
  }
}

// ---------------- combined [K-input | K-input2 | R] fragged weights (stages 2..6) -----
__global__ __launch_bounds__(256) void prep_comb(const float* __restrict__ Kmat,
                                                 const float* __restrict__ Rmat,
                                                 u16* __restrict__ dst,
                                                 int N, int U, int w1v, int w1p,
                                                 int w2v, int w2p, int Ks, int JT,
                                                 int total_fid) {
  int t = blockIdx.x * 256 + threadIdx.x;
  int lane = t & 63, fid = t >> 6;
  if (fid >= total_fid) return;
  int l15 = lane & 15, quad = lane >> 4;
  int ks = fid % Ks;
  int rest = fid / Ks;
  int jt = rest % JT;
  int g = rest / JT;
  int j = jt * 16 + l15;
  bool jv = (j < U);
  int n = g * U + (jv ? j : 0);
  u16* o = dst + ((size_t)fid * 64 + lane) * 8;
#pragma unroll
  for (int jj = 0; jj < 8; ++jj) {
    int k = ks * 32 + quad * 8 + jj;
    float v = 0.f;
    if (jv) {
      if (k < w1p) {
        if (k < w1v) v = Kmat[(size_t)k * N + n];
      } else if (k < w1p + w2p) {
        int kr = k - w1p;
        if (kr < w2v) v = Kmat[(size_t)(w1v + kr) * N + n];
      } else {
        int rr = k - w1p - w2p;
        if (rr < U) v = Rmat[(size_t)rr * N + n];
      }
    }
    o[jj] = (u16)f2b(v);
  }
}

// ---------------- MFMA GEMM (L1 xp only): C[M,3072] = A[M,512]bf16 @ W + bias -------
__global__ __launch_bounds__(256) void gemm_mfma(const u16* __restrict__ A, int strideA, int Kact,
                                                 const u16* __restrict__ Bf,
                                                 const float* __restrict__ bias,
                                                 float* __restrict__ C,
                                                 int N, int Ntiles, int Ks,
                                                 int t0, int tcLog2) {
  __shared__ char sha[16 * 2056];
  const int tid = threadIdx.x;
  const int lane = tid & 63, l15 = lane & 15, quad = lane >> 4, w = tid >> 6;
  const int KS4 = Ks * 8;
  const int rowB = Ks * 64 + 8;
  const int bm = blockIdx.y * 16;

  for (int i = tid; i < 16 * KS4; i += 256) {
    int r = i / KS4, u = i - r * KS4;
    u64 v = 0;
    if (u * 4 < Kact) {
      int rl = bm + r;
      size_t grow;
      if (t0 >= 0) {
        int tcm = (1 << tcLog2) - 1;
        grow = (((size_t)(rl >> tcLog2)) << 9) + t0 + (rl & tcm);
      } else {
        grow = (size_t)rl;
      }
      v = *((const u64*)(A + grow * (size_t)strideA) + u);
    }
    *(u64*)(sha + r * rowB + u * 8) = v;
  }
  __syncthreads();

  f4v acc[4];
  f4v z4 = {0.f, 0.f, 0.f, 0.f};
#pragma unroll
  for (int q = 0; q < 4; ++q) acc[q] = z4;

  const int ntb = blockIdx.x * 16 + w * 4;
  for (int ks = 0; ks < Ks; ++ks) {
    int off = l15 * rowB + ks * 64 + quad * 16;
    s8v a = *(const s8v*)(sha + off);
#pragma unroll
    for (int q = 0; q < 4; ++q) {
      int nt = ntb + q;
      if (nt < Ntiles) {
        s8v b = *(const s8v*)(Bf + (((size_t)nt * Ks + ks) * 64 + lane) * 8);
        acc[q] = __builtin_amdgcn_mfma_f32_16x16x32_bf16(a, b, acc[q], 0, 0, 0);
      }
    }
  }
#pragma unroll
  for (int q = 0; q < 4; ++q) {
    int nt = ntb + q;
    if (nt >= Ntiles) continue;
    int col = nt * 16 + l15;
    if (col < N) {
      float bv = bias[col];
#pragma unroll
      for (int r = 0; r < 4; ++r) {
        int rowl = bm + quad * 4 + r;
        C[(size_t)rowl * N + col] = acc[q][r] + bv;
      }
    }
  }
}

// ---------------- generic stage config ----------------
struct GCfg {
  const u16 *s1, *s2;        // input row-buffers [row][w?p] bf16
  const u16* Bf;             // combined fragged weights
  const float* bias;         // [2][3U]
  u16* ydst;                 // bf16 out rows [row][Upad] (or null)
  float* fdst;               // fp32 out (or null)
  u16* hglob;                // nb>1: [2][32][Upad] LLC; nb==1: hsave [32][Upad]
  int w1p, w2p, Upad, U, Ks, ksIn, JT, nb, base, act, wfd;
  int baseA, na, baseB, nbb; // producer flag polls (>= t+1)
  int pubF, pubN;            // flag replica publish range: consumers pubF..pubF+pubN-1
};

// LDS map: L1 path: h tile [32 rows][2048B +16 pad] = 66048, then K-split
// partial-sum area 3 gates x 12 waves x 64 lanes x 16B = 36864.
// stage_gen path: Ab [0..74240), Hp [74240..) (nb==1 stages, Upad=32 only).
#define REDOFF 66048
#define SMEM_BYTES 102912
#define HPOFF 74240

// ---------------- stage L1: 32 blocks x 1024 thr ----------------------------
__device__ __attribute__((noinline)) void stage_l1(
    const float* xp, const u16* Bf, const float* brec, u16* hbuf, u16* yout,
    u32* flags, int t0, int tc, char* smem) {
  const int tid = threadIdx.x;
  const int lane = tid & 63, l15 = lane & 15, quad = (lane >> 4) & 3;
  const int w = tid >> 6;             // 0..15
  const int kq = w >> 2;              // 0..3 : ks range [kq*8, kq*8+8)
  const int jt_l = (w >> 1) & 1;
  const int Mt = w & 1;
  const int blk = blockIdx.x;         // 0..31
  const int jt = blk * 2 + jt_l;
  const int j = jt * 16 + l15;
  const int HP = 32 * 1024;
  const bool own = (kq == 0);

  float bz = 0.f, brr = 0.f, bh = 0.f;
  float hprev[4];
  if (own) {
    bz = brec[j]; brr = brec[1024 + j]; bh = brec[2048 + j];
    const u32* hp = (const u32*)(hbuf + (size_t)(t0 & 1) * HP);
#pragma unroll
    for (int r = 0; r < 4; ++r) {
      int b = Mt * 16 + quad * 4 + r;
      u32 wd = ldW(hp + ((b * 1024 + (j & ~1)) >> 1));
      hprev[r] = b2f((j & 1) ? (u16)(wd >> 16) : (u16)(wd & 0xffff));
    }
  }

  for (int tt = 0; tt < tc; ++tt) {
    const int t = t0 + tt;
    waitP(flags, 0, 32, (u32)t, 0, 0, 0, 0, 0, 0);
    // xp NT loads first (longest latency); they stay in flight across the
    // lean barriers below and are consumed in the epilogue.
    float xv[3][4];
    if (own) {
#pragma unroll
      for (int r = 0; r < 4; ++r) {
        int b = Mt * 16 + quad * 4 + r;
        const float* xr_ = xp + ((size_t)b * tc + tt) * 3072;
        xv[0][r] = __builtin_nontemporal_load(xr_ + j);
        xv[1][r] = __builtin_nontemporal_load(xr_ + 1024 + j);
        xv[2][r] = __builtin_nontemporal_load(xr_ + 2048 + j);
      }
    }
    // stage h -> LDS: 4096x16B over 1024 threads = 4 pipelined loads
    {
      const char* hsrc = (const char*)(hbuf + (size_t)(t & 1) * HP);
      f4v vals[4];
#pragma unroll
      for (int i = 0; i < 4; ++i)
        vals[i] = load16_sc(hsrc + (size_t)(tid + i * 1024) * 16);
      vm_wait0();
#pragma unroll
      for (int i = 0; i < 4; ++i) {
        int g16 = tid + i * 1024;
        *(f4v*)(smem + (g16 >> 7) * 2064 + (g16 & 127) * 16) = vals[i];
      }
    }
    bar_lgkm();   // staging visible; xp/B loads NOT drained
    f4v acc[3];
    f4v z4 = {0.f, 0.f, 0.f, 0.f};
#pragma unroll
    for (int g = 0; g < 3; ++g) acc[g] = z4;
#pragma unroll
    for (int i = 0; i < 8; ++i) {
      int ks = kq * 8 + i;
      s8v a = *(const s8v*)(smem + (Mt * 16 + l15) * 2064 + ks * 64 + quad * 16);
#pragma unroll
      for (int g = 0; g < 3; ++g) {
        s8v b = *(const s8v*)(Bf + (((size_t)(g * 64 + jt) * 32 + ks) * 64 + lane) * 8);
        acc[g] = __builtin_amdgcn_mfma_f32_16x16x32_bf16(a, b, acc[g], 0, 0, 0);
      }
    }
    if (!own) {
      int idx = (kq - 1) * 4 + (w & 3);
#pragma unroll
      for (int g = 0; g < 3; ++g)
        *(f4v*)(smem + REDOFF + ((g * 12 + idx) * 64 + lane) * 16) = acc[g];
    }
    bar_lgkm();   // partials visible; vmcnt untouched
    if (own) {
#pragma unroll
      for (int g = 0; g < 3; ++g)
#pragma unroll
        for (int kk = 0; kk < 3; ++kk) {
          f4v p = *(const f4v*)(smem + REDOFF + ((g * 12 + kk * 4 + w) * 64 + lane) * 16);
          acc[g] += p;
        }
      u16* hdst = hbuf + (size_t)((t + 1) & 1) * HP;
#pragma unroll
      for (int r = 0; r < 4; ++r) {
        int b = Mt * 16 + quad * 4 + r;
        size_t row = (size_t)b * tc + tt;
        float z = sigm(xv[0][r] + acc[0][r] + bz);
        float rr = sigm(xv[1][r] + acc[1][r] + brr);
        float hh = fmaxf(xv[2][r] + rr * (acc[2][r] + bh), 0.f);
        float hnew = z * hprev[r] + (1.f - z) * hh;
        hprev[r] = hnew;
        float part = __shfl_xor(hnew, 1, 64);
        if ((l15 & 1) == 0) {
          u32 wd = (u32)(u16)f2b(hnew) | ((u32)(u16)f2b(part) << 16);
          stW((u32*)hdst + ((b * 1024 + j) >> 1), wd);
          stW((u32*)yout + ((row * 1024 + j) >> 1), wd);
        }
      }
      vm_wait0();  // only owner waves have data stores to drain
    }
    bar0();        // all owners drained -> publish is a valid release
    // publish: one scatter store, lane -> consumer block replica.
    if (tid < 40) stW(&flags[(blk * 64 + tid) * 32], (u32)(t + 1));
  }
}

// ---------------- generic fused stage (L2..L6), 1024 threads ----------------
__device__ __attribute__((noinline)) void stage_gen(
    const GCfg& c, int bs, u32* flags, int t0, int tc, int initH, char* smem) {
  const int tid = threadIdx.x;
  const int lane = tid & 63, l15 = lane & 15, quad = (lane >> 4) & 3;
  const int w = tid >> 6;  // 0..15
  const int Kc = c.w1p + c.w2p + c.Upad;
  const int rowA = Kc * 2 + 16;
  const int rowH = c.Upad * 2 + 16;
  char* Ab = smem;
  char* Hp = smem + HPOFF;
  const int HB = 32 * rowH;
  const int uIn = (c.w1p + c.w2p) >> 3;
  const int uH = c.Upad >> 3;
  const int upr = uIn + ((c.nb > 1) ? uH : 0);
  const int total_units = 32 * upr;
  const int u1 = c.w1p >> 3;
  const int U = c.U;
  const int HPstride = 32 * c.Upad;

  const int ntask = c.JT * 2;
  int tcount = 0;
  int tjt[2], tmt[2];
#pragma unroll
  for (int i = 0; i < 2; ++i) {
    int task = w * c.nb + bs + i * 16 * c.nb;
    if (task < ntask) { tjt[tcount] = task >> 1; tmt[tcount] = task & 1; ++tcount; }
  }

  const float* b0 = c.bias;
  const float* b1 = c.bias + 3 * U;
  float bz[2], br_[2], bih[2], brh[2];
  int jl[2];
  bool jv[2];
#pragma unroll
  for (int i = 0; i < 2; ++i) {
    if (i >= tcount) { jv[i] = false; jl[i] = 0; bz[i] = br_[i] = bih[i] = brh[i] = 0.f; continue; }
    int j = tjt[i] * 16 + l15;
    jv[i] = (j < U);
    int jc = jv[i] ? j : 0;
    jl[i] = j;
    bz[i] = b0[jc] + b1[jc];
    br_[i] = b0[U + jc] + b1[U + jc];
    bih[i] = b0[2 * U + jc];
    brh[i] = b1[2 * U + jc];
  }

  if (c.nb == 1) {
    for (int i = tid; i < (2 * HB) >> 2; i += 1024) ((u32*)Hp)[i] = 0;
    __syncthreads();
    if (!initH) {
      for (int i = tid; i < 32 * uH; i += 1024) {
        int m = i / uH, u = i - m * uH;
        *(f4v*)(Hp + (t0 & 1) * HB + m * rowH + u * 16) = *((const f4v*)c.hglob + i);
      }
    }
    __syncthreads();
  }

  float hprev[2][4];
#pragma unroll
  for (int i = 0; i < 2; ++i) {
    if (i >= tcount) continue;
#pragma unroll
    for (int r = 0; r < 4; ++r) {
      int b = tmt[i] * 16 + quad * 4 + r;
      float hv;
      if (c.nb > 1) {
        u32 wd = ldW((const u32*)c.hglob + (((t0 & 1) * HPstride + b * c.Upad + (jl[i] & ~1)) >> 1));
        hv = b2f((jl[i] & 1) ? (u16)(wd >> 16) : (u16)(wd & 0xffff));
      } else {
        hv = b2f(*(const u16*)(Hp + (t0 & 1) * HB + b * rowH + jl[i] * 2));
      }
      hprev[i][r] = jv[i] ? hv : 0.f;
    }
  }

  for (int tt = 0; tt < tc; ++tt) {
    const int t = t0 + tt;
    waitP(flags, c.baseA, c.na, (u32)(t + 1), c.baseB, c.nbb, (u32)(t + 1),
          c.base, (c.nb > 1) ? c.nb : 0, (u32)t);
    // ---- stage A (inputs [+h if nb>1]) into LDS ----
    {
      f4v vals[5];
      int offs[5];
#pragma unroll
      for (int i = 0; i < 5; ++i) {
        int idx = tid + i * 1024;
        int pidx = (idx < total_units) ? idx : (total_units - 1);
        int m = pidx / upr, u = pidx - m * upr;
        const char* src;
        if (u < u1)
          src = (const char*)c.s1 + ((size_t)(m * tc + tt) * c.w1p + (u << 3)) * 2;
        else if (u < uIn)
          src = (const char*)c.s2 + ((size_t)(m * tc + tt) * c.w2p + ((u - u1) << 3)) * 2;
        else
          src = (const char*)c.hglob + ((size_t)(t & 1) * HPstride + m * c.Upad + ((u - uIn) << 3)) * 2;
        vals[i] = load16_sc(src);
        offs[i] = m * rowA + u * 16;
      }
      vm_wait0();
#pragma unroll
      for (int i = 0; i < 5; ++i)
        if (tid + i * 1024 < total_units) *(f4v*)(Ab + offs[i]) = vals[i];
    }
    bar_lgkm();   // staging visible; B-fragment loads keep flowing
    // ---- MFMA: input-K part (z,r,xh), then h part (z,r,rh) ----
    f4v az[2], ar[2], axh[2], arh[2];
    f4v z4 = {0.f, 0.f, 0.f, 0.f};
#pragma unroll
    for (int i = 0; i < 2; ++i) { az[i] = z4; ar[i] = z4; axh[i] = z4; arh[i] = z4; }
    for (int ks = 0; ks < c.ksIn; ++ks) {
#pragma unroll
      for (int i = 0; i < 2; ++i) {
        if (i >= tcount) break;
        s8v a = *(const s8v*)(Ab + (tmt[i] * 16 + l15) * rowA + ks * 64 + quad * 16);
        const u16* bb = c.Bf + ((size_t)tjt[i] * c.Ks + ks) * 512 + lane * 8;
        s8v bz_ = *(const s8v*)(bb);
        s8v br2 = *(const s8v*)(bb + (size_t)c.JT * c.Ks * 512);
        s8v bh2 = *(const s8v*)(bb + (size_t)2 * c.JT * c.Ks * 512);
        az[i] = __builtin_amdgcn_mfma_f32_16x16x32_bf16(a, bz_, az[i], 0, 0, 0);
        ar[i] = __builtin_amdgcn_mfma_f32_16x16x32_bf16(a, br2, ar[i], 0, 0, 0);
        axh[i] = __builtin_amdgcn_mfma_f32_16x16x32_bf16(a, bh2, axh[i], 0, 0, 0);
      }
    }
    for (int ks = c.ksIn; ks < c.Ks; ++ks) {
#pragma unroll
      for (int i = 0; i < 2; ++i) {
        if (i >= tcount) break;
        s8v a;
        if (c.nb > 1)
          a = *(const s8v*)(Ab + (tmt[i] * 16 + l15) * rowA + ks * 64 + quad * 16);
        else
          a = *(const s8v*)(Hp + (t & 1) * HB + (tmt[i] * 16 + l15) * rowH + (ks - c.ksIn) * 64 + quad * 16);
        const u16* bb = c.Bf + ((size_t)tjt[i] * c.Ks + ks) * 512 + lane * 8;
        s8v bz_ = *(const s8v*)(bb);
        s8v br2 = *(const s8v*)(bb + (size_t)c.JT * c.Ks * 512);
        s8v bh2 = *(const s8v*)(bb + (size_t)2 * c.JT * c.Ks * 512);
        az[i] = __builtin_amdgcn_mfma_f32_16x16x32_bf16(a, bz_, az[i], 0, 0, 0);
        ar[i] = __builtin_amdgcn_mfma_f32_16x16x32_bf16(a, br2, ar[i], 0, 0, 0);
        arh[i] = __builtin_amdgcn_mfma_f32_16x16x32_bf16(a, bh2, arh[i], 0, 0, 0);
      }
    }
    // ---- gates + publish ----
#pragma unroll
    for (int i = 0; i < 2; ++i) {
      if (i >= tcount) break;
#pragma unroll
      for (int r = 0; r < 4; ++r) {
        int b = tmt[i] * 16 + quad * 4 + r;
        size_t row = (size_t)b * tc + tt;
        float z = sigm(az[i][r] + bz[i]);
        float rg = sigm(ar[i][r] + br_[i]);
        float hh = axh[i][r] + bih[i] + rg * (arh[i][r] + brh[i]);
        if (c.act) hh = fmaxf(hh, 0.f);
        float hnew = z * hprev[i][r] + (1.f - z) * hh;
        if (!jv[i]) hnew = 0.f;
        hprev[i][r] = hnew;
        int j = jl[i];
        float part = __shfl_xor(hnew, 1, 64);
        u32 wd = (u32)(u16)f2b(hnew) | ((u32)(u16)f2b(part) << 16);
        if ((l15 & 1) == 0) {
          if (c.ydst) stW((u32*)c.ydst + ((row * c.Upad + j) >> 1), wd);
          if (c.nb > 1)
            stW((u32*)c.hglob + ((((t + 1) & 1) * HPstride + b * c.Upad + j) >> 1), wd);
        }
        if (c.nb == 1) *(u16*)(Hp + ((t + 1) & 1) * HB + b * rowH + j * 2) = (u16)f2b(hnew);
        if (c.fdst && jv[i] && j < c.wfd)
          c.fdst[((size_t)b * TT + t) * c.wfd + j] = hnew;
      }
    }
    vm_wait0();   // cheap for non-store waves (their loads drained at staging)
    bar0();       // all data stores drained -> publish is a valid release
    if (tid < c.pubN)
      stW(&flags[((c.base + bs) * 64 + c.pubF + tid) * 32], (u32)(t + 1));
  }
  if (c.nb == 1) {
    int pf = (t0 + tc) & 1;
    for (int i = tid; i < 32 * uH; i += 1024) {
      int m = i / uH, u = i - m * uH;
      *((f4v*)c.hglob + i) = *(const f4v*)(Hp + pf * HB + m * rowH + u * 16);
    }
  }
}

// ---------------- the pipeline kernel: 54 blocks x 1024 ----------------
// slots: L1=0..31, L2=32..39, L3=40, L4=41..48, L5=49..52, L6=53
__global__ __launch_bounds__(1024, 1) void pipeline(
    const float* xp, const u16* BfL1, const float* brecL1, u16* hbufL1, u16* y1c,
    GCfg c1, GCfg c2, GCfg c3, GCfg c4, GCfg c5,
    u32* flags, int t0, int tc, int initH) {
  __shared__ char smem[SMEM_BYTES];
  int blk = blockIdx.x;
  if (blk < 32) stage_l1(xp, BfL1, brecL1, hbufL1, y1c, flags, t0, tc, smem);
  else if (blk < 40) stage_gen(c1, blk - 32, flags, t0, tc, initH, smem);
  else if (blk < 41) stage_gen(c2, 0, flags, t0, tc, initH, smem);
  else if (blk < 49) stage_gen(c3, blk - 41, flags, t0, tc, initH, smem);
  else if (blk < 53) stage_gen(c4, blk - 49, flags, t0, tc, initH, smem);
  else stage_gen(c5, 0, flags, t0, tc, initH, smem);
}

// ---------------- host launch ----------------
extern "C" void kernel_launch(void* const* d_in, const int* in_sizes, int n_in,
                              void* d_out, int out_size, void* d_ws, size_t ws_size,
                              hipStream_t stream) {
  const float* x = (const float*)d_in[0];

  // R10: try Tc=128 first (halves pipeline dispatch boundaries, each costing a
  // full drain/refill ~100us); falls back to 64/32/16 if workspace is small.
  int tcLog2 = 7;
  {
    size_t fixed = (size_t)16384 * 512 * 2
                   + (3145728ull + 1572864ull + 442368 + 15360 + 319488 + 147456 + 7680) * 2
                   + 700000;
    for (; tcLog2 >= 4; --tcLog2) {
      size_t rc = (size_t)BB << tcLog2;
      size_t per = rc * 3072 * 4 + rc * (1024 + 128 + 32 + 256 + 128) * 2 + 8192;
      if (fixed + per <= ws_size || tcLog2 == 4) break;
    }
  }
  const int Tc = 1 << tcLog2;
  const int NCk = TT / Tc;
  const size_t RC = (size_t)BB * Tc;

  char* ws = (char*)d_ws;
  size_t off = 0;
  auto alloc = [&](size_t bytes) -> char* {
    char* p = ws + off;
    off += (bytes + 255) & ~(size_t)255;
    return p;
  };

  u32* flags = (u32*)alloc((size_t)54 * 64 * 32 * sizeof(u32));
  u16* hbufL1 = (u16*)alloc((size_t)2 * 32 * 1024 * 2);
  u16* hb2 = (u16*)alloc((size_t)2 * 32 * 128 * 2);
  u16* hb4 = (u16*)alloc((size_t)2 * 32 * 256 * 2);
  u16* hb5 = (u16*)alloc((size_t)2 * 32 * 128 * 2);
  u16* hs3 = (u16*)alloc((size_t)32 * 32 * 2);
  u16* hs6 = (u16*)alloc((size_t)32 * 32 * 2);
  u16* recB1 = (u16*)alloc(3145728ull * 2);
  u16* gemB1 = (u16*)alloc(1572864ull * 2);
  u16* cB[5];
  const size_t cBe[5] = {442368, 15360, 319488, 147456, 7680};
  for (int i = 0; i < 5; ++i) cB[i] = (u16*)alloc(cBe[i] * 2);
  u16* x16 = (u16*)alloc((size_t)16384 * 512 * 2);
  float* xp = (float*)alloc(RC * 3072 * sizeof(float));
  u16* y1c = (u16*)alloc(RC * 1024 * 2);
  u16* y2c = (u16*)alloc(RC * 128 * 2);
  u16* yec = (u16*)alloc(RC * 32 * 2);
  u16* y4c = (u16*)alloc(RC * 256 * 2);
  u16* y5c = (u16*)alloc(RC * 128 * 2);

  float* outye = (float*)d_out;
  float* outyd = outye + (size_t)BB * TT * 23;

  hipMemsetAsync(flags, 0, (size_t)54 * 64 * 32 * sizeof(u32), stream);
  hipMemsetAsync(hbufL1, 0, (size_t)2 * 32 * 1024 * 2, stream);
  hipMemsetAsync(hb2, 0, (size_t)2 * 32 * 128 * 2, stream);
  hipMemsetAsync(hb4, 0, (size_t)2 * 32 * 256 * 2, stream);
  hipMemsetAsync(hb5, 0, (size_t)2 * 32 * 128 * 2, stream);

  {
    int n4 = (16384 * 512) / 4;
    hipLaunchKernelGGL(cast_bf16, dim3((n4 + 255) / 256), dim3(256), 0, stream, x, x16, n4);
    hipLaunchKernelGGL(prep_frags, dim3((3 * 64 * 32 * 64 + 255) / 256), dim3(256), 0, stream,
                       (const float*)d_in[2], recB1, 3072, 1024, 32, 64, 1024, 1, 3 * 64 * 32);
    hipLaunchKernelGGL(prep_frags, dim3((192 * 16 * 64 + 255) / 256), dim3(256), 0, stream,
                       (const float*)d_in[1], gemB1, 3072, 512, 16, 0, 0, 0, 192 * 16);
    const int pc[5][8] = {
        {384, 128, 1024, 1024, 0, 0, 36, 8},   // L2
        {69, 23, 128, 128, 0, 0, 5, 2},        // L3
        {768, 256, 128, 128, 23, 32, 13, 16},  // L4
        {384, 128, 256, 256, 0, 0, 12, 8},     // L5
        {24, 8, 128, 128, 0, 0, 5, 1}};        // L6
    for (int i = 0; i < 5; ++i) {
      int l = i + 1;
      int tf = 3 * pc[i][7] * pc[i][6];
      hipLaunchKernelGGL(prep_comb, dim3((tf * 64 + 255) / 256), dim3(256), 0, stream,
                         (const float*)d_in[1 + 3 * l], (const float*)d_in[2 + 3 * l], cB[i],
                         pc[i][0], pc[i][1], pc[i][2], pc[i][3], pc[i][4], pc[i][5],
                         pc[i][6], pc[i][7], tf);
    }
  }

  // slots: L1=0..31, L2=32..39, L3=40, L4=41..48, L5=49..52, L6=53
  // pub ranges: L1->consumers 0..39 (hardcoded in stage_l1);
  // L2(32..39)->32..48; L3(40)->41..48; L4(41..48)->41..52; L5(49..52)->49..53.
  GCfg c1 = {y1c, nullptr, cB[0], (const float*)d_in[6], y2c, nullptr, hb2,
             1024, 0, 128, 128, 36, 32, 8, 8, 32, 1, 0, 0, 32, 0, 0, 32, 17};
  GCfg c2 = {y2c, nullptr, cB[1], (const float*)d_in[9], yec, outye, hs3,
             128, 0, 32, 23, 5, 4, 2, 1, 40, 0, 23, 32, 8, 0, 0, 41, 8};
  GCfg c3 = {y2c, yec, cB[2], (const float*)d_in[12], y4c, nullptr, hb4,
             128, 32, 256, 256, 13, 5, 16, 8, 41, 1, 0, 32, 8, 40, 1, 41, 12};
  GCfg c4 = {y4c, nullptr, cB[3], (const float*)d_in[15], y5c, nullptr, hb5,
             256, 0, 128, 128, 12, 8, 8, 4, 49, 1, 0, 41, 8, 0, 0, 49, 5};
  GCfg c5 = {y5c, nullptr, cB[4], (const float*)d_in[18], nullptr, outyd, hs6,
             128, 0, 32, 8, 5, 4, 1, 1, 53, 0, 8, 49, 4, 0, 0, 0, 0};

  const float* biasL1 = (const float*)d_in[3];

  for (int c = 0; c < NCk; ++c) {
    const int t0 = c * Tc;
    hipLaunchKernelGGL(gemm_mfma, dim3(12, (unsigned)(RC / 16)), dim3(256), 0, stream,
                       x16, 512, 512, gemB1, biasL1, xp, 3072, 192, 16, t0, tcLog2);
    hipLaunchKernelGGL(pipeline, dim3(54), dim3(1024), 0, stream,
                       xp, recB1, biasL1 + 3072, hbufL1, y1c,
                       c1, c2, c3, c4, c5, flags, t0, Tc, (c == 0) ? 1 : 0);
  }
}